// Round 1
// 2085.007 us; speedup vs baseline: 1.3435x; 1.3435x over previous
//
#include <hip/hip_runtime.h>
#include <stdint.h>

#define SEQ 4096
#define DIM 4096
#define NH 32
#define NKV 8
#define HD 128
// GEMM: M=16384 (4*4096), N=6144 (q 4096 | k 1024 | v 1024), K=4096. fp32 I/O.
// 256x256 tile, BK=32, 8 waves (2M x 4N), wave tile 128x64, mfma_f32_16x16x32_bf16.
// fp32 global -> regs -> bf16 cvt -> XOR-swizzled LDS (2 x 32KB double buffer).
// 2-phase pipeline: next-tile global loads issued before ds_read+MFMA; single
// barrier per K-step; cvt+ds_write after sched_barrier so vmcnt wait hides
// under the MFMA cluster.

typedef __bf16 bf16x8 __attribute__((ext_vector_type(8)));
typedef __bf16 bf16x4 __attribute__((ext_vector_type(4)));
typedef float f32x4 __attribute__((ext_vector_type(4)));

__global__ __launch_bounds__(512, 2)
void qkv_rope_kernel(const float* __restrict__ x,
                     const float* __restrict__ wq,
                     const float* __restrict__ wk,
                     const float* __restrict__ wv,
                     const float* __restrict__ cosT,
                     const float* __restrict__ sinT,
                     float* __restrict__ out) {
    // per buffer: A bf16 [256 rows][32 k] = 16 KB at +0, B = 16 KB at +16384.
    // row = 64 B = 4 chunks of 16 B (k-octets); phys chunk = logical ^ (row&3).
    __shared__ __align__(16) char smem[2 * 32768];

    const int t = threadIdx.x;
    const int lane = t & 63;
    const int w = t >> 6;
    const int bn = blockIdx.x;   // 0..23 fastest -> W + current x slabs L3-resident
    const int bm = blockIdx.y;   // 0..63

    const float* W;
    int n_mat;
    if (bn < 16)      { W = wq; n_mat = bn << 8; }
    else if (bn < 20) { W = wk; n_mat = (bn - 16) << 8; }
    else              { W = wv; n_mat = (bn - 20) << 8; }

    const int m0 = bm << 8;

    // ---- staging geometry: thread t owns fp32 chunk (t&7) of rows (t>>3)+64p ----
    const int srow = t >> 3;          // 0..63
    const int sc   = t & 7;           // fp32 4-float chunk in row
    // bf16 dest: k-octet = sc>>1 (xor-swizzled), half = sc&1
    const int sdso = srow * 64 + (((sc >> 1) ^ (srow & 3)) * 16) + (sc & 1) * 8;

    const float* ga = x + (size_t)(m0 + srow) * DIM + sc * 4;
    const float* gb = W + (size_t)(n_mat + srow) * DIM + sc * 4;

    // ---- fragment geometry ----
    const int wm = (w & 1) << 7;   // wave m offset: 0/128
    const int wn = (w >> 1) << 6;  // wave n offset: 0/64/128/192
    const int fr = lane & 15;      // fragment row
    const int q4 = lane >> 4;      // k-octet: frag holds k = q4*8 .. q4*8+7
    const int sw = (q4 ^ (fr & 3)) * 16;   // swizzled 16B chunk offset

    int offA[8], offB[4];
#pragma unroll
    for (int i = 0; i < 8; i++) offA[i] = (wm + i * 16 + fr) * 64 + sw;
#pragma unroll
    for (int j = 0; j < 4; j++) offB[j] = 16384 + (wn + j * 16 + fr) * 64 + sw;

    f32x4 acc[8][4];
#pragma unroll
    for (int i = 0; i < 8; i++)
#pragma unroll
        for (int j = 0; j < 4; j++)
            acc[i][j] = (f32x4){0.f, 0.f, 0.f, 0.f};

    f32x4 rA[4], rB[4];

#define STAGE_LOAD() do {                                                   \
    _Pragma("unroll")                                                       \
    for (int p = 0; p < 4; p++) {                                           \
        rA[p] = *(const f32x4*)(ga + (size_t)p * 64 * DIM);                 \
        rB[p] = *(const f32x4*)(gb + (size_t)p * 64 * DIM);                 \
    }                                                                       \
    ga += 32; gb += 32;                                                     \
} while (0)

#define STAGE_WRITE(buf) do {                                               \
    char* dst = smem + (buf) * 32768;                                       \
    _Pragma("unroll")                                                       \
    for (int p = 0; p < 4; p++) {                                           \
        bf16x4 va, vb;                                                      \
        _Pragma("unroll")                                                   \
        for (int e = 0; e < 4; e++) {                                       \
            va[e] = (__bf16)rA[p][e];                                       \
            vb[e] = (__bf16)rB[p][e];                                       \
        }                                                                   \
        *(bf16x4*)(dst + p * 4096 + sdso) = va;                             \
        *(bf16x4*)(dst + 16384 + p * 4096 + sdso) = vb;                     \
    }                                                                       \
} while (0)

#define COMPUTE(buf) do {                                                   \
    const char* srcb = smem + (buf) * 32768;                                \
    bf16x8 bfr[4];                                                          \
    _Pragma("unroll")                                                       \
    for (int j = 0; j < 4; j++) bfr[j] = *(const bf16x8*)(srcb + offB[j]);  \
    _Pragma("unroll")                                                       \
    for (int i = 0; i < 8; i++) {                                           \
        const bf16x8 af = *(const bf16x8*)(srcb + offA[i]);                 \
        _Pragma("unroll")                                                   \
        for (int j = 0; j < 4; j++)                                         \
            acc[i][j] = __builtin_amdgcn_mfma_f32_16x16x32_bf16(            \
                af, bfr[j], acc[i][j], 0, 0, 0);                            \
    }                                                                       \
} while (0)

    // prologue: tile 0 -> buf 0
    STAGE_LOAD();
    STAGE_WRITE(0);
    __syncthreads();

    // 128 K-tiles total; explicit x2 unroll keeps all LDS addresses static
    for (int it = 0; it < 126; it += 2) {
        STAGE_LOAD();                          // tile it+1 -> regs (async)
        COMPUTE(0);                            // tile it from buf0
        __builtin_amdgcn_sched_barrier(0);     // keep vmcnt-wait after MFMAs
        STAGE_WRITE(1);                        // tile it+1 -> buf1
        __syncthreads();

        STAGE_LOAD();                          // tile it+2
        COMPUTE(1);                            // tile it+1
        __builtin_amdgcn_sched_barrier(0);
        STAGE_WRITE(0);                        // tile it+2 -> buf0
        __syncthreads();
    }
    // it = 126
    STAGE_LOAD();                              // tile 127
    COMPUTE(0);                                // tile 126
    __builtin_amdgcn_sched_barrier(0);
    STAGE_WRITE(1);
    __syncthreads();
    COMPUTE(1);                                // tile 127

    // ---- epilogue: RoPE (q,k) + transposed (b,h,s,d) store, fp32 ----
    const size_t QSZ = (size_t)4 * NH * SEQ * HD;
    const size_t KSZ = (size_t)4 * NKV * SEQ * HD;
    size_t region, bstr;
    bool do_rope;
    if (bn < 16)      { region = 0;         bstr = (size_t)NH  * SEQ * HD; do_rope = true; }
    else if (bn < 20) { region = QSZ;       bstr = (size_t)NKV * SEQ * HD; do_rope = true; }
    else              { region = QSZ + KSZ; bstr = (size_t)NKV * SEQ * HD; do_rope = false; }

    const int col_l = lane & 15;
#pragma unroll
    for (int j = 0; j < 4; j++) {
        const int n_local = n_mat + wn + j * 16 + col_l;
        const int h = n_local >> 7;
        const int d = n_local & 127;
        const int fidx = d >> 1;
        const size_t base_j = region + (size_t)h * (SEQ * HD) + d;
#pragma unroll
        for (int i = 0; i < 8; i++) {
            const int mrow = m0 + wm + i * 16 + q4 * 4;
#pragma unroll
            for (int r = 0; r < 4; r++) {
                const int m = mrow + r;
                const int b = m >> 12;          // SEQ = 4096
                const int s = m & (SEQ - 1);
                float v = acc[i][j][r];
                if (do_rope) {
                    const float cv = cosT[s * 64 + fidx];
                    const float sv = sinT[s * 64 + fidx];
                    const float other = __shfl_xor(v, 1, 64);
                    // even d: t1*c - t2*s ; odd d: t1*s + t2*c
                    v = (d & 1) ? fmaf(v, cv, other * sv) : fmaf(v, cv, -other * sv);
                }
                out[base_j + (size_t)b * bstr + (size_t)s * HD] = v;
            }
        }
    }
#undef STAGE_LOAD
#undef STAGE_WRITE
#undef COMPUTE
}

extern "C" void kernel_launch(void* const* d_in, const int* in_sizes, int n_in,
                              void* d_out, int out_size, void* d_ws, size_t ws_size,
                              hipStream_t stream) {
    const float* x    = (const float*)d_in[0];
    const float* wq   = (const float*)d_in[1];
    const float* wk   = (const float*)d_in[2];
    const float* wv   = (const float*)d_in[3];
    const float* cosT = (const float*)d_in[4];
    const float* sinT = (const float*)d_in[5];
    float* out = (float*)d_out;

    dim3 grid(24, 64);   // bn fastest (W + x-slab stay L3-resident), bm slabs
    dim3 block(512);
    qkv_rope_kernel<<<grid, block, 0, stream>>>(x, wq, wk, wv, cosT, sinT, out);
}

// Round 2
// 1863.864 us; speedup vs baseline: 1.5029x; 1.1186x over previous
//
#include <hip/hip_runtime.h>
#include <stdint.h>

#define SEQ 4096
#define DIM 4096
#define NH 32
#define NKV 8
#define HD 128
// GEMM: M=16384 (4*4096), N=6144 (q 4096 | k 1024 | v 1024), K=4096.
// Pass 1: fp32 -> bf16 one-time conversion into workspace (x -> xb, wq|wk|wv -> wb).
// Pass 2: 256x256x(BK=64) 8-phase GEMM per learn_hip m201 template:
//   global_load_lds direct staging, 2x64KB LDS double buffer, 3-bit XOR swizzle,
//   counted vmcnt (8 at ph4, 6 at ph8), setprio around MFMA clusters.
// Epilogue: RoPE (q,k) + transposed (b,h,s,d) fp32 store.

typedef __bf16 bf16x8 __attribute__((ext_vector_type(8)));
typedef __bf16 bf16x4 __attribute__((ext_vector_type(4)));
typedef float f32x4 __attribute__((ext_vector_type(4)));

__device__ __forceinline__ void gl_lds16(const void* g, void* l) {
    __builtin_amdgcn_global_load_lds(
        (const __attribute__((address_space(1))) void*)g,
        (__attribute__((address_space(3))) void*)l, 16, 0, 0);
}

// ---------------- pass 1: fp32 -> bf16 conversion ----------------
__global__ __launch_bounds__(256)
void cvt_kernel(const float* __restrict__ x,
                const float* __restrict__ wq,
                const float* __restrict__ wk,
                const float* __restrict__ wv,
                __bf16* __restrict__ xb,
                __bf16* __restrict__ wb) {
    const size_t NX = 16777216;   // x: 67.1M floats / 4
    const size_t NQ = 4194304;    // wq: 16.8M / 4
    const size_t NK = 1048576;    // wk
    const size_t NV = 1048576;    // wv
    const size_t NT = NX + NQ + NK + NV;
    for (size_t g = (size_t)blockIdx.x * 256 + threadIdx.x; g < NT;
         g += (size_t)gridDim.x * 256) {
        const float* s; __bf16* d; size_t off;
        if (g < NX)                { s = x;  d = xb;            off = g; }
        else if (g < NX + NQ)      { s = wq; d = wb;            off = g - NX; }
        else if (g < NX + NQ + NK) { s = wk; d = wb + 16777216; off = g - NX - NQ; }
        else                       { s = wv; d = wb + 20971520; off = g - NX - NQ - NK; }
        const f32x4 v = *(const f32x4*)(s + off * 4);
        bf16x4 o;
#pragma unroll
        for (int e = 0; e < 4; e++) o[e] = (__bf16)v[e];
        *(bf16x4*)(d + off * 4) = o;
    }
}

// ---------------- pass 2: 8-phase 256^2 GEMM + RoPE epilogue ----------------
// LDS per dbuf (64 KB): A rows 0..255 at +0 (row*128B), B rows 0..255 at +32768.
// Swizzle: phys_byte = lin ^ ((row&7)<<4)  (flips bits 4-6 of the 128B row).
__global__ __launch_bounds__(512, 2)
void qkv8_kernel(const __bf16* __restrict__ xb,
                 const __bf16* __restrict__ wb,
                 const float* __restrict__ cosT,
                 const float* __restrict__ sinT,
                 float* __restrict__ out) {
    extern __shared__ char sm[];

    const int t = threadIdx.x;
    const int lane = t & 63;
    const int w = t >> 6;
    const int bn = blockIdx.x;   // 0..23
    const int bm = blockIdx.y;   // 0..63

    int n_mat;                   // row offset within the source matrix (for output)
    if (bn < 16)      n_mat = bn << 8;
    else if (bn < 20) n_mat = (bn - 16) << 8;
    else              n_mat = (bn - 20) << 8;

    const int m0 = bm << 8;

    // ---- staging geometry (pre-swizzled global source, linear LDS dest) ----
    const int row_r = t >> 3;                              // 0..63
    const int colE  = ((t & 7) ^ (row_r & 7)) << 3;        // element col = swz(colb)/2
    const size_t eAbase = (size_t)(m0 + row_r) * DIM + colE;
    const size_t eBbase = (size_t)(bn * 256 + row_r) * DIM + colE;

    // ---- fragment geometry ----
    const int wm = (w & 1) << 7;   // 0/128
    const int wn = (w >> 1) << 6;  // 0/64/128/192
    const int fr = lane & 15;
    const int q4 = lane >> 4;      // k-octet

    int aoff[2][4], boff[2][2];
#pragma unroll
    for (int mh = 0; mh < 2; mh++)
#pragma unroll
        for (int i = 0; i < 4; i++) {
            const int row = wm + mh * 64 + i * 16 + fr;
            aoff[mh][i] = row * 128 + ((q4 * 16) ^ ((row & 7) << 4));
        }
#pragma unroll
    for (int nh = 0; nh < 2; nh++)
#pragma unroll
        for (int j = 0; j < 2; j++) {
            const int row = wn + nh * 32 + j * 16 + fr;
            boff[nh][j] = 32768 + row * 128 + ((q4 * 16) ^ ((row & 7) << 4));
        }

    f32x4 acc[8][4];
#pragma unroll
    for (int i = 0; i < 8; i++)
#pragma unroll
        for (int j = 0; j < 4; j++)
            acc[i][j] = (f32x4){0.f, 0.f, 0.f, 0.f};

    bf16x8 Ar[8], B0r[4], B1r[4];

#define LDA(MH, DB) do { _Pragma("unroll") \
    for (int i_ = 0; i_ < 4; i_++) { \
        Ar[i_*2]   = *(const bf16x8*)(sm + (DB)*65536 + aoff[MH][i_]); \
        Ar[i_*2+1] = *(const bf16x8*)(sm + (DB)*65536 + (aoff[MH][i_] ^ 64)); \
    } } while (0)

#define LDB(BR, NHh, DB) do { _Pragma("unroll") \
    for (int j_ = 0; j_ < 2; j_++) { \
        BR[j_*2]   = *(const bf16x8*)(sm + (DB)*65536 + boff[NHh][j_]); \
        BR[j_*2+1] = *(const bf16x8*)(sm + (DB)*65536 + (boff[NHh][j_] ^ 64)); \
    } } while (0)

#define QUAD(MH, NHh, BR) do { _Pragma("unroll") \
    for (int i_ = 0; i_ < 4; i_++) { _Pragma("unroll") \
        for (int j_ = 0; j_ < 2; j_++) { \
            f32x4 c_ = acc[(MH)*4+i_][(NHh)*2+j_]; \
            c_ = __builtin_amdgcn_mfma_f32_16x16x32_bf16(Ar[i_*2],   BR[j_*2],   c_, 0, 0, 0); \
            c_ = __builtin_amdgcn_mfma_f32_16x16x32_bf16(Ar[i_*2+1], BR[j_*2+1], c_, 0, 0, 0); \
            acc[(MH)*4+i_][(NHh)*2+j_] = c_; \
        } } } while (0)

    // half-tile stage: 2 global_load_lds per thread (p=0: rows r..r+63, p=1: +64)
#define STG_A(H, TILE, DB) do { \
    gl_lds16(xb + eAbase + (H)*524288 + (size_t)(TILE)*64, \
             sm + (DB)*65536 + (H)*16384 + w*1024); \
    gl_lds16(xb + eAbase + (H)*524288 + 262144 + (size_t)(TILE)*64, \
             sm + (DB)*65536 + (H)*16384 + 8192 + w*1024); } while (0)
#define STG_B(H, TILE, DB) do { \
    gl_lds16(wb + eBbase + (H)*524288 + (size_t)(TILE)*64, \
             sm + (DB)*65536 + 32768 + (H)*16384 + w*1024); \
    gl_lds16(wb + eBbase + (H)*524288 + 262144 + (size_t)(TILE)*64, \
             sm + (DB)*65536 + 32768 + (H)*16384 + 8192 + w*1024); } while (0)

#define PH_MID() do { \
    asm volatile("" ::: "memory"); \
    __builtin_amdgcn_s_barrier(); \
    asm volatile("s_waitcnt lgkmcnt(0)" ::: "memory"); \
    __builtin_amdgcn_sched_barrier(0); \
    __builtin_amdgcn_s_setprio(1); } while (0)
#define PH_END() do { \
    __builtin_amdgcn_s_setprio(0); \
    asm volatile("" ::: "memory"); \
    __builtin_amdgcn_s_barrier(); \
    asm volatile("" ::: "memory"); } while (0)
#define PH_END_VM(N) do { \
    __builtin_amdgcn_s_setprio(0); \
    asm volatile("s_waitcnt vmcnt(" #N ")" ::: "memory"); \
    __builtin_amdgcn_s_barrier(); \
    asm volatile("" ::: "memory"); } while (0)

    // ---- prologue: tile0 full -> buf0; tile1 {B0,A0,A1} -> buf1 (14 insts/wave) ----
    STG_A(0, 0, 0); STG_A(1, 0, 0); STG_B(0, 0, 0); STG_B(1, 0, 0);
    STG_B(0, 1, 1); STG_A(0, 1, 1); STG_A(1, 1, 1);
    asm volatile("s_waitcnt vmcnt(6)" ::: "memory");   // tile0 landed; 3 half-tiles in flight
    __builtin_amdgcn_s_barrier();
    asm volatile("" ::: "memory");

    // ---- main loop: 31 iterations x 2 K-tiles (tiles 0..61) ----
    for (int T = 0; T < 62; T += 2) {
        // ph1: quad(0,0) of tile T (buf0); stage B1 of T+1 -> buf1
        LDA(0, 0); LDB(B0r, 0, 0); STG_B(1, T + 1, 1);
        PH_MID(); QUAD(0, 0, B0r); PH_END();
        // ph2: quad(0,1)
        LDB(B1r, 1, 0);
        PH_MID(); QUAD(0, 1, B1r); PH_END();
        // ph3: quad(1,1); stage B0,B1 of T+2 -> buf0 (B region free after ph2)
        LDA(1, 0); STG_B(0, T + 2, 0); STG_B(1, T + 2, 0);
        PH_MID(); QUAD(1, 1, B1r); PH_END();
        // ph4: quad(1,0); stage A0,A1 of T+2 -> buf0 (A region free after ph3)
        STG_A(0, T + 2, 0); STG_A(1, T + 2, 0);
        PH_MID(); QUAD(1, 0, B0r); PH_END_VM(8);        // tile T+1 fully landed
        // ph5: quad(0,0) of tile T+1 (buf1)
        LDA(0, 1); LDB(B0r, 0, 1);
        PH_MID(); QUAD(0, 0, B0r); PH_END();
        // ph6
        LDB(B1r, 1, 1);
        PH_MID(); QUAD(0, 1, B1r); PH_END();
        // ph7: stage B0 of T+3 -> buf1 (B free after ph6)
        LDA(1, 1); STG_B(0, T + 3, 1);
        PH_MID(); QUAD(1, 1, B1r); PH_END();
        // ph8: stage A0,A1 of T+3 -> buf1 (A free after ph7)
        STG_A(0, T + 3, 1); STG_A(1, T + 3, 1);
        PH_MID(); QUAD(1, 0, B0r); PH_END_VM(6);        // tile T+2 fully landed
    }

    // ---- epilogue: tiles 62 (buf0) and 63 (buf1) ----
    LDA(0, 0); LDB(B0r, 0, 0); STG_B(1, 63, 1);
    PH_MID(); QUAD(0, 0, B0r); PH_END();
    LDB(B1r, 1, 0);
    PH_MID(); QUAD(0, 1, B1r); PH_END();
    LDA(1, 0);
    PH_MID(); QUAD(1, 1, B1r); PH_END();
    PH_MID(); QUAD(1, 0, B0r); PH_END_VM(0);            // tile 63 fully landed
    LDA(0, 1); LDB(B0r, 0, 1);
    PH_MID(); QUAD(0, 0, B0r); PH_END();
    LDB(B1r, 1, 1);
    PH_MID(); QUAD(0, 1, B1r); PH_END();
    LDA(1, 1);
    PH_MID(); QUAD(1, 1, B1r); PH_END();
    PH_MID(); QUAD(1, 0, B0r);
    __builtin_amdgcn_s_setprio(0);

#undef LDA
#undef LDB
#undef QUAD
#undef STG_A
#undef STG_B
#undef PH_MID
#undef PH_END
#undef PH_END_VM

    // ---- RoPE (q,k) + transposed (b,h,s,d) store, fp32 ----
    const size_t QSZ = (size_t)4 * NH * SEQ * HD;
    const size_t KSZ = (size_t)4 * NKV * SEQ * HD;
    size_t region, bstr;
    bool do_rope;
    if (bn < 16)      { region = 0;         bstr = (size_t)NH  * SEQ * HD; do_rope = true; }
    else if (bn < 20) { region = QSZ;       bstr = (size_t)NKV * SEQ * HD; do_rope = true; }
    else              { region = QSZ + KSZ; bstr = (size_t)NKV * SEQ * HD; do_rope = false; }

    const int col_l = lane & 15;
#pragma unroll
    for (int j = 0; j < 4; j++) {
        const int n_local = n_mat + wn + j * 16 + col_l;
        const int h = n_local >> 7;
        const int d = n_local & 127;
        const int fidx = d >> 1;
        const size_t base_j = region + (size_t)h * (SEQ * HD) + d;
#pragma unroll
        for (int i = 0; i < 8; i++) {
            const int mrow = m0 + wm + i * 16 + q4 * 4;
#pragma unroll
            for (int r = 0; r < 4; r++) {
                const int m = mrow + r;
                const int b = m >> 12;          // SEQ = 4096
                const int s = m & (SEQ - 1);
                float v = acc[i][j][r];
                if (do_rope) {
                    const float cv = cosT[s * 64 + fidx];
                    const float sv = sinT[s * 64 + fidx];
                    const float other = __shfl_xor(v, 1, 64);
                    v = (d & 1) ? fmaf(v, cv, other * sv) : fmaf(v, cv, -other * sv);
                }
                out[base_j + (size_t)b * bstr + (size_t)s * HD] = v;
            }
        }
    }
}

// ---------------- fallback (round-1 kernel) if workspace too small ----------------
__global__ __launch_bounds__(512, 2)
void qkv_rope_fallback(const float* __restrict__ x,
                       const float* __restrict__ wq,
                       const float* __restrict__ wk,
                       const float* __restrict__ wv,
                       const float* __restrict__ cosT,
                       const float* __restrict__ sinT,
                       float* __restrict__ out) {
    __shared__ __align__(16) char smem[2 * 32768];

    const int t = threadIdx.x;
    const int lane = t & 63;
    const int w = t >> 6;
    const int bn = blockIdx.x;
    const int bm = blockIdx.y;

    const float* W;
    int n_mat;
    if (bn < 16)      { W = wq; n_mat = bn << 8; }
    else if (bn < 20) { W = wk; n_mat = (bn - 16) << 8; }
    else              { W = wv; n_mat = (bn - 20) << 8; }

    const int m0 = bm << 8;
    const int srow = t >> 3;
    const int sc   = t & 7;
    const int sdso = srow * 64 + (((sc >> 1) ^ (srow & 3)) * 16) + (sc & 1) * 8;

    const float* ga = x + (size_t)(m0 + srow) * DIM + sc * 4;
    const float* gb = W + (size_t)(n_mat + srow) * DIM + sc * 4;

    const int wm = (w & 1) << 7;
    const int wn = (w >> 1) << 6;
    const int fr = lane & 15;
    const int q4 = lane >> 4;
    const int sw = (q4 ^ (fr & 3)) * 16;

    int offA[8], offB[4];
#pragma unroll
    for (int i = 0; i < 8; i++) offA[i] = (wm + i * 16 + fr) * 64 + sw;
#pragma unroll
    for (int j = 0; j < 4; j++) offB[j] = 16384 + (wn + j * 16 + fr) * 64 + sw;

    f32x4 acc[8][4];
#pragma unroll
    for (int i = 0; i < 8; i++)
#pragma unroll
        for (int j = 0; j < 4; j++)
            acc[i][j] = (f32x4){0.f, 0.f, 0.f, 0.f};

    f32x4 rA[4], rB[4];

#define FB_LOAD() do { _Pragma("unroll") \
    for (int p = 0; p < 4; p++) { \
        rA[p] = *(const f32x4*)(ga + (size_t)p * 64 * DIM); \
        rB[p] = *(const f32x4*)(gb + (size_t)p * 64 * DIM); \
    } ga += 32; gb += 32; } while (0)

#define FB_WRITE(buf) do { \
    char* dst = smem + (buf) * 32768; \
    _Pragma("unroll") \
    for (int p = 0; p < 4; p++) { \
        bf16x4 va, vb; \
        _Pragma("unroll") \
        for (int e = 0; e < 4; e++) { va[e] = (__bf16)rA[p][e]; vb[e] = (__bf16)rB[p][e]; } \
        *(bf16x4*)(dst + p * 4096 + sdso) = va; \
        *(bf16x4*)(dst + 16384 + p * 4096 + sdso) = vb; \
    } } while (0)

#define FB_COMPUTE(buf) do { \
    const char* srcb = smem + (buf) * 32768; \
    bf16x8 bfr[4]; \
    _Pragma("unroll") \
    for (int j = 0; j < 4; j++) bfr[j] = *(const bf16x8*)(srcb + offB[j]); \
    _Pragma("unroll") \
    for (int i = 0; i < 8; i++) { \
        const bf16x8 af = *(const bf16x8*)(srcb + offA[i]); \
        _Pragma("unroll") \
        for (int j = 0; j < 4; j++) \
            acc[i][j] = __builtin_amdgcn_mfma_f32_16x16x32_bf16(af, bfr[j], acc[i][j], 0, 0, 0); \
    } } while (0)

    FB_LOAD();
    FB_WRITE(0);
    __syncthreads();
    for (int it = 0; it < 126; it += 2) {
        FB_LOAD(); FB_COMPUTE(0);
        __builtin_amdgcn_sched_barrier(0);
        FB_WRITE(1); __syncthreads();
        FB_LOAD(); FB_COMPUTE(1);
        __builtin_amdgcn_sched_barrier(0);
        FB_WRITE(0); __syncthreads();
    }
    FB_LOAD(); FB_COMPUTE(0);
    __builtin_amdgcn_sched_barrier(0);
    FB_WRITE(1); __syncthreads();
    FB_COMPUTE(1);
#undef FB_LOAD
#undef FB_WRITE
#undef FB_COMPUTE

    const size_t QSZ = (size_t)4 * NH * SEQ * HD;
    const size_t KSZ = (size_t)4 * NKV * SEQ * HD;
    size_t region, bstr;
    bool do_rope;
    if (bn < 16)      { region = 0;         bstr = (size_t)NH  * SEQ * HD; do_rope = true; }
    else if (bn < 20) { region = QSZ;       bstr = (size_t)NKV * SEQ * HD; do_rope = true; }
    else              { region = QSZ + KSZ; bstr = (size_t)NKV * SEQ * HD; do_rope = false; }

    const int col_l = lane & 15;
#pragma unroll
    for (int j = 0; j < 4; j++) {
        const int n_local = n_mat + wn + j * 16 + col_l;
        const int h = n_local >> 7;
        const int d = n_local & 127;
        const int fidx = d >> 1;
        const size_t base_j = region + (size_t)h * (SEQ * HD) + d;
#pragma unroll
        for (int i = 0; i < 8; i++) {
            const int mrow = m0 + wm + i * 16 + q4 * 4;
#pragma unroll
            for (int r = 0; r < 4; r++) {
                const int m = mrow + r;
                const int b = m >> 12;
                const int s = m & (SEQ - 1);
                float v = acc[i][j][r];
                if (do_rope) {
                    const float cv = cosT[s * 64 + fidx];
                    const float sv = sinT[s * 64 + fidx];
                    const float other = __shfl_xor(v, 1, 64);
                    v = (d & 1) ? fmaf(v, cv, other * sv) : fmaf(v, cv, -other * sv);
                }
                out[base_j + (size_t)b * bstr + (size_t)s * HD] = v;
            }
        }
    }
}

extern "C" void kernel_launch(void* const* d_in, const int* in_sizes, int n_in,
                              void* d_out, int out_size, void* d_ws, size_t ws_size,
                              hipStream_t stream) {
    const float* x    = (const float*)d_in[0];
    const float* wq   = (const float*)d_in[1];
    const float* wk   = (const float*)d_in[2];
    const float* wv   = (const float*)d_in[3];
    const float* cosT = (const float*)d_in[4];
    const float* sinT = (const float*)d_in[5];
    float* out = (float*)d_out;

    const size_t XB_BYTES = (size_t)16384 * 4096 * 2;   // 134,217,728
    const size_t WB_BYTES = (size_t)6144 * 4096 * 2;    //  50,331,648

    if (ws_size >= XB_BYTES + WB_BYTES) {
        __bf16* xb = (__bf16*)d_ws;
        __bf16* wb = (__bf16*)((char*)d_ws + XB_BYTES);
        static bool attr_done = false;
        if (!attr_done) {
            (void)hipFuncSetAttribute((const void*)qkv8_kernel,
                                      hipFuncAttributeMaxDynamicSharedMemorySize, 131072);
            attr_done = true;
        }
        cvt_kernel<<<dim3(8192), dim3(256), 0, stream>>>(x, wq, wk, wv, xb, wb);
        qkv8_kernel<<<dim3(24, 64), dim3(512), 131072, stream>>>(xb, wb, cosT, sinT, out);
    } else {
        qkv_rope_fallback<<<dim3(24, 64), dim3(512), 0, stream>>>(x, wq, wk, wv, cosT, sinT, out);
    }
}